// Round 1
// baseline (441.772 us; speedup 1.0000x reference)
//
#include <hip/hip_runtime.h>
#include <hip/hip_bf16.h>

#define B_   8
#define C_   1024
#define HW_  4096
#define NK   21
#define NT   32                      // 128-row tiling used by kprop
#define NT2  16                      // 256-row tiling used by kgram
#define NTRI2 (NT2 * (NT2 + 1) / 2)  // 136 upper-triangle 256x256 tiles

using bf16 = __hip_bfloat16;
typedef __attribute__((ext_vector_type(4))) float float4_;
typedef __attribute__((ext_vector_type(8))) int int8v;

#define WAITV(n) asm volatile("s_waitcnt vmcnt(" #n ")" ::: "memory")
#define FENCE()  asm volatile("" ::: "memory")
#define BARRIER() do { FENCE(); __builtin_amdgcn_s_barrier(); FENCE(); } while (0)

// ---- kernel 1: transpose + fp8-quantize (UNNORMALIZED) + sumsq reduction ----
__global__ __launch_bounds__(256) void ktrans(const float* __restrict__ x4, float* __restrict__ sumsq,
                                              unsigned char* __restrict__ Xq) {
    int b = blockIdx.z, ct = blockIdx.y, jt = blockIdx.x;
    int c0 = ct * 128, j0 = jt * 64;
    int t = threadIdx.x;
    __shared__ float tile[128][65];   // [c][j]
    __shared__ float ssq[64];

    int jl = t & 63, cl = t >> 6;
    if (t < 64) ssq[t] = 0.f;
    __syncthreads();
    float part = 0.f;
#pragma unroll
    for (int cc = 0; cc < 128; cc += 4) {
        float v = x4[((size_t)b * C_ + c0 + cc + cl) * HW_ + j0 + jl];
        tile[cc + cl][jl] = v;
        part = fmaf(v, v, part);
    }
    atomicAdd(&ssq[jl], part);
    __syncthreads();

    int j = t >> 2, q = t & 3;
    int jg = j0 + j;
    unsigned int pk[8];
#pragma unroll
    for (int g = 0; g < 8; ++g) {
        float f0 = tile[q * 32 + g * 4 + 0][j];
        float f1 = tile[q * 32 + g * 4 + 1][j];
        float f2 = tile[q * 32 + g * 4 + 2][j];
        float f3 = tile[q * 32 + g * 4 + 3][j];
        unsigned int r = 0;
        r = __builtin_amdgcn_cvt_pk_fp8_f32(f0, f1, r, false);
        r = __builtin_amdgcn_cvt_pk_fp8_f32(f2, f3, r, true);
        pk[g] = r;
    }
    unsigned char* dst = Xq + ((size_t)b * HW_ + jg) * C_ + c0 + q * 32;
    *(uint4*)(dst)      = make_uint4(pk[0], pk[1], pk[2], pk[3]);
    *(uint4*)(dst + 16) = make_uint4(pk[4], pk[5], pk[6], pk[7]);

    if (t < 64) atomicAdd(&sumsq[b * HW_ + j0 + t], ssq[t]);
}

// ---- kernel 2: symmetric gram, 256x256 tile, 8-wave, double-buffered,
// counted-vmcnt pipeline (loads stay in flight across raw s_barriers; vmcnt
// never drained to 0 in the main loop). Per K-step per wave: 24 ds_read_b128
// (B frags reused across both m-half MFMA clusters) + 32 mfma_scale
// 16x16x128. XCD-aware: XCD = blockIdx%8 owns one batch -> its 4 MiB Xq
// slice fits exactly one XCD's L2.
__global__ __launch_bounds__(512, 2) void kgram(const unsigned char* __restrict__ Xq,
                                                const float* __restrict__ sumsq, bf16* __restrict__ aff,
                                                float* __restrict__ colsum, int* __restrict__ flags) {
    int lin = blockIdx.x;
    int b = lin & 7;                 // XCD id == batch id (1088 = 8*136 blocks)
    int p = lin >> 3;                // sequential triangle index per XCD
    int it = (int)((2.0f * NT2 + 1.0f - sqrtf((2.0f * NT2 + 1.0f) * (2.0f * NT2 + 1.0f) - 8.0f * (float)p)) * 0.5f);
    while (it > 0 && p < it * NT2 - it * (it - 1) / 2) --it;
    while (p >= (it + 1) * NT2 - (it + 1) * it / 2) ++it;
    int jt = it + p - (it * NT2 - it * (it - 1) / 2);

    int i0 = it * 256, j0 = jt * 256;
    int tid = threadIdx.x, w = tid >> 6, l = tid & 63;
    int wr = w >> 2, wc = w & 3;      // 2x4 wave grid; per-wave output 128x64
    int lrow = l & 15, lk = l >> 4;

    __shared__ __align__(16) unsigned char smem[131072];   // [A0 B0 A1 B1] x 32 KiB
    __shared__ int fl;

    const unsigned char* XA = Xq + ((size_t)b * HW_ + i0) * C_;
    const unsigned char* XB = Xq + ((size_t)b * HW_ + j0) * C_;

    int rhi = tid >> 3, sl = tid & 7, gp = sl ^ (rhi & 7);   // XOR pre-swizzle of global src

    auto stg = [&](int bo, const unsigned char* g, int k0) {
#pragma unroll
        for (int q = 0; q < 4; ++q) {
            int R = q * 64 + rhi;
            __builtin_amdgcn_global_load_lds(
                (const __attribute__((address_space(1))) void*)(g + (size_t)R * C_ + k0 + (gp << 4)),
                (__attribute__((address_space(3))) void*)(smem + bo + R * 128 + (sl << 4)), 16, 0, 0);
        }
    };

    auto ldfrag = [&](const unsigned char* base, int r) {
        int sw = r & 7;
        uint4 lo = *(const uint4*)(base + r * 128 + (((lk * 2) ^ sw) << 4));
        uint4 hi = *(const uint4*)(base + r * 128 + (((lk * 2 + 1) ^ sw) << 4));
        int8v v; v[0] = lo.x; v[1] = lo.y; v[2] = lo.z; v[3] = lo.w;
        v[4] = hi.x; v[5] = hi.y; v[6] = hi.z; v[7] = hi.w;
        return v;
    };

    float4_ acc[8][4];
#pragma unroll
    for (int m = 0; m < 8; ++m)
#pragma unroll
        for (int n = 0; n < 4; ++n) acc[m][n] = {0.f, 0.f, 0.f, 0.f};

    auto ck = [&](int bo) {
        const unsigned char* A  = smem + bo;
        const unsigned char* Bb = smem + bo + 32768;
        int8v bv[4];
#pragma unroll
        for (int n = 0; n < 4; ++n) bv[n] = ldfrag(Bb, wc * 64 + n * 16 + lrow);
        int8v av[4];
#pragma unroll
        for (int m = 0; m < 4; ++m) av[m] = ldfrag(A, wr * 128 + m * 16 + lrow);
        __builtin_amdgcn_s_setprio(1);
#pragma unroll
        for (int m = 0; m < 4; ++m)
#pragma unroll
            for (int n = 0; n < 4; ++n)
                acc[m][n] = __builtin_amdgcn_mfma_scale_f32_16x16x128_f8f6f4(
                    av[m], bv[n], acc[m][n], 0, 0, 0, 0x7f7f7f7f, 0, 0x7f7f7f7f);
        __builtin_amdgcn_s_setprio(0);
#pragma unroll
        for (int m = 0; m < 4; ++m) av[m] = ldfrag(A, wr * 128 + (m + 4) * 16 + lrow);
        __builtin_amdgcn_s_setprio(1);
#pragma unroll
        for (int m = 0; m < 4; ++m)
#pragma unroll
            for (int n = 0; n < 4; ++n)
                acc[m + 4][n] = __builtin_amdgcn_mfma_scale_f32_16x16x128_f8f6f4(
                    av[m], bv[n], acc[m + 4][n], 0, 0, 0, 0x7f7f7f7f, 0, 0x7f7f7f7f);
        __builtin_amdgcn_s_setprio(0);
    };

    // prologue: K0 -> buf0, K1 -> buf1 (8 loads/thread each; 16 in flight)
    stg(0, XA, 0);        stg(32768, XB, 0);
    stg(65536, XA, 128);  stg(98304, XB, 128);

    for (int tt2 = 0; tt2 < 3; ++tt2) {
        int kb = tt2 * 256;
        WAITV(8);                                   // my buf0 loads landed
        BARRIER();                                  // everyone's landed
        ck(0);                                      // K = kb
        BARRIER();                                  // all waves done reading buf0
        stg(0, XA, kb + 256); stg(32768, XB, kb + 256);
        WAITV(8);                                   // buf1 ready (oldest 8)
        BARRIER();
        ck(65536);                                  // K = kb + 128
        BARRIER();                                  // all waves done reading buf1
        stg(65536, XA, kb + 384); stg(98304, XB, kb + 384);
    }
    // tail: K6 in buf0, K7 in buf1
    WAITV(8);
    BARRIER();
    ck(0);
    WAITV(0);
    BARRIER();
    ck(65536);

    // ---- epilogue: deferred normalization rn_i * rn_j ----
    float rnj[4];
#pragma unroll
    for (int n = 0; n < 4; ++n) {
        int j = j0 + wc * 64 + n * 16 + lrow;
        rnj[n] = 1.0f / fmaxf(sqrtf(sumsq[b * HW_ + j]), 1e-12f);
    }
    float rni[8][4];
#pragma unroll
    for (int m = 0; m < 8; ++m)
#pragma unroll
        for (int r = 0; r < 4; ++r) {
            int i = i0 + wr * 128 + m * 16 + lk * 4 + r;
            rni[m][r] = 1.0f / fmaxf(sqrtf(sumsq[b * HW_ + i]), 1e-12f);
        }
    bool any = false;
#pragma unroll
    for (int m = 0; m < 8; ++m)
#pragma unroll
        for (int n = 0; n < 4; ++n)
#pragma unroll
            for (int r = 0; r < 4; ++r) {
                acc[m][n][r] *= rni[m][r] * rnj[n];
                any |= (acc[m][n][r] >= 0.5f);
            }

    if (tid == 0) fl = 0;
    __syncthreads();
    unsigned long long bal = __ballot(any);
    if (l == 0 && bal != 0ull) atomicOr(&fl, 1);
    __syncthreads();
    bool mirror = (it != jt);
    if (tid == 0) {
        flags[(b * NT2 + it) * NT2 + jt] = fl;
        if (mirror) flags[(b * NT2 + jt) * NT2 + it] = fl;
    }

    if (fl) {
        size_t affb = (size_t)b * HW_ * HW_;
        float rsum[8][4];
#pragma unroll
        for (int m = 0; m < 8; ++m)
#pragma unroll
            for (int r = 0; r < 4; ++r) rsum[m][r] = 0.f;

#pragma unroll
        for (int n = 0; n < 4; ++n) {
            int j = j0 + wc * 64 + n * 16 + lrow;
            float cs = 0.f;
#pragma unroll
            for (int m = 0; m < 8; ++m) {
#pragma unroll
                for (int r = 0; r < 4; ++r) {
                    float v = acc[m][n][r];
                    v = fminf(fmaxf(v, 0.01f), 0.999f);
                    v = (v < 0.5f) ? 0.0f : v;
                    bf16 bb = __float2bfloat16(v);
                    int i = i0 + wr * 128 + m * 16 + lk * 4 + r;
                    aff[affb + (size_t)i * HW_ + j] = bb;
                    float bf = __bfloat162float(bb);
                    cs += bf;
                    rsum[m][r] += bf;
                    if (mirror) aff[affb + (size_t)j * HW_ + i] = bb;
                }
            }
            cs += __shfl_xor(cs, 16);
            cs += __shfl_xor(cs, 32);
            if (lk == 0) atomicAdd(&colsum[b * HW_ + j], cs);
        }
        if (mirror) {
#pragma unroll
            for (int m = 0; m < 8; ++m) {
#pragma unroll
                for (int r = 0; r < 4; ++r) {
                    float s = rsum[m][r];
                    s += __shfl_xor(s, 1);
                    s += __shfl_xor(s, 2);
                    s += __shfl_xor(s, 4);
                    s += __shfl_xor(s, 8);
                    if (lrow == 0) {
                        int i = i0 + wr * 128 + m * 16 + lk * 4 + r;
                        atomicAdd(&colsum[b * HW_ + i], s);
                    }
                }
            }
        }
    }
}

// ---- kernel 3: out[k][j] = (sum_i lf[k][i]*aff[i][j]) / colsum[j] -----------
__global__ __launch_bounds__(128) void kprop(const float* __restrict__ lf, const bf16* __restrict__ aff,
                                             const int* __restrict__ flags, const float* __restrict__ colsum,
                                             float* __restrict__ outp) {
    int b = blockIdx.y, jt = blockIdx.x;
    int t = threadIdx.x;                 // 128 threads
    int j = jt * 128 + t;
    __shared__ float lfs[NK * 128];
    float acc[NK];
#pragma unroll
    for (int k = 0; k < NK; ++k) acc[k] = 0.f;

    for (int it = 0; it < NT; ++it) {
        // flags now at 256-tile granularity
        if (flags[(b * NT2 + (it >> 1)) * NT2 + (jt >> 1)] == 0) continue;
        __syncthreads();
        for (int idx = t; idx < NK * 128; idx += 128)
            lfs[idx] = lf[((size_t)b * NK + (idx >> 7)) * HW_ + it * 128 + (idx & 127)];
        __syncthreads();
        const bf16* ap = aff + ((size_t)b * HW_ + it * 128) * HW_ + j;
        for (int ii = 0; ii < 128; ++ii) {
            float a = __bfloat162float(ap[(size_t)ii * HW_]);
#pragma unroll
            for (int k = 0; k < NK; ++k)
                acc[k] = fmaf(lfs[(k << 7) + ii], a, acc[k]);
        }
    }
    float inv = 1.0f / colsum[b * HW_ + j];
#pragma unroll
    for (int k = 0; k < NK; ++k)
        outp[((size_t)b * NK + k) * HW_ + j] = acc[k] * inv;
}

extern "C" void kernel_launch(void* const* d_in, const int* in_sizes, int n_in,
                              void* d_out, int out_size, void* d_ws, size_t ws_size,
                              hipStream_t stream) {
    const float* x4 = (const float*)d_in[0];
    const float* logits = (const float*)d_in[1];
    float* out = (float*)d_out;

    char* w = (char*)d_ws;
    size_t off = 0;
    auto take = [&](size_t bytes) {
        char* p = w + off;
        off += (bytes + 255) & ~(size_t)255;
        return p;
    };
    unsigned char* Xq = (unsigned char*)take((size_t)B_ * HW_ * C_);    // 32 MiB
    bf16* aff     = (bf16*)take((size_t)B_ * HW_ * HW_ * 2);            // 256 MiB
    float* colsum = (float*)take((size_t)B_ * HW_ * 4);
    int*   flags  = (int*)take((size_t)B_ * NT2 * NT2 * 4);
    float* sumsq  = (float*)take((size_t)B_ * HW_ * 4);
    float* lf1    = (float*)take((size_t)B_ * NK * HW_ * 4);

    hipMemsetAsync(colsum, 0,
                   (size_t)B_ * HW_ * 4 + (size_t)B_ * NT2 * NT2 * 4 + (size_t)B_ * HW_ * 4, stream);

    ktrans<<<dim3(HW_ / 64, C_ / 128, B_), dim3(256), 0, stream>>>(x4, sumsq, Xq);
    kgram <<<dim3(NTRI2 * B_), dim3(512), 0, stream>>>(Xq, sumsq, aff, colsum, flags);

    kprop<<<dim3(NT, B_), dim3(128), 0, stream>>>(logits, aff, flags, colsum, lf1);
    kprop<<<dim3(NT, B_), dim3(128), 0, stream>>>(lf1, aff, flags, colsum, out);
}